// Round 10
// baseline (2364.089 us; speedup 1.0000x reference)
//
#include <hip/hip_runtime.h>
#include <hip/hip_fp16.h>

#define TT 2048
#define BB 64
#define HH 128
#define GG 512  // 4H

typedef _Float16 f16x8 __attribute__((ext_vector_type(8)));
typedef float f32x4 __attribute__((ext_vector_type(4)));

__device__ __forceinline__ float sigm(float x) {
    return __builtin_amdgcn_rcpf(1.0f + __expf(-x));
}
__device__ __forceinline__ float tanh_f(float x) {
    return 1.0f - 2.0f * __builtin_amdgcn_rcpf(1.0f + __expf(2.0f * x));
}
// LDS-only barrier: no vmcnt drain.
__device__ __forceinline__ void bar_lds() {
    asm volatile("s_waitcnt lgkmcnt(0)\n\ts_barrier" ::: "memory");
}

__device__ __forceinline__ f16x8 load_frag(const float* rowp, int kt, int lh) {
    const float4* p4 = (const float4*)(rowp + kt * 32 + lh * 8);
    float4 a = p4[0], b = p4[1];
    f16x8 f;
    f[0] = (_Float16)a.x; f[1] = (_Float16)a.y; f[2] = (_Float16)a.z; f[3] = (_Float16)a.w;
    f[4] = (_Float16)b.x; f[5] = (_Float16)b.y; f[6] = (_Float16)b.z; f[7] = (_Float16)b.w;
    return f;
}

// Wave-specialized 3-stage pipeline (round-8/9 structure, proven correct).
// 1 batch/block, 64 blocks, 768 thr = 12 waves = 3 groups of 4:
//   G0: h0[i]   = act(x[i]*v + u0 + W_hh0.h0[i-1])
//   G1: q1[i-1] = b1 + W_ih1.h0[i-1]             -> LDS Q1 double-buffer
//   G2: h1[i-2] = act(q1[i-2] + W_hh1.h1[i-3])   -> pooling
// Round-10 fix: the Bw fragments are pinned with an opaque asm def so the
// allocator CANNOT rematerialize them by reloading from global each interval
// (rounds 8/9: VGPR_Count=84 -> weights re-fetched every interval through
// L2/L3, ~2650 cyc/interval). Opaque def => must stay live: 128 frag regs +
// av 16 + ~20 scalars ~= 164 <= 168 available at waves_per_eu(3,3).
__global__ __attribute__((amdgpu_flat_work_group_size(768, 768),
                          amdgpu_waves_per_eu(3, 3))) void k_mega(
    const float* __restrict__ x, const int* __restrict__ lengths,
    const float* __restrict__ ff_w, const float* __restrict__ ff_b,
    const float* __restrict__ W_ih0, const float* __restrict__ W_hh0,
    const float* __restrict__ b0, const float* __restrict__ W_ih1,
    const float* __restrict__ W_hh1, const float* __restrict__ b1,
    float* __restrict__ pooled) {
    const int b = blockIdx.x;
    const int tid = threadIdx.x;
    const int w = tid >> 6;
    const int grp = w >> 2;   // 0: W_hh0, 1: W_ih1, 2: W_hh1
    const int wg = w & 3;     // wave-in-group
    const int lane = tid & 63;
    const int c = lane & 15;
    const int lh = lane >> 4;
    __shared__ float xs[TT];
    __shared__ _Float16 Hb0[2][HH];
    __shared__ _Float16 Hb1[2][HH];
    __shared__ float Q1[2][GG];
    __shared__ float Vb[GG], Ub[GG], Bb[GG];

    for (int i = tid; i < TT; i += 768) xs[i] = x[b * TT + i];
    if (tid < 2 * HH) {
        ((_Float16*)Hb0)[tid] = (_Float16)0.f;
        ((_Float16*)Hb1)[tid] = (_Float16)0.f;
    }
    if (tid < GG) {  // rank-1 x-projection folded per row + biases -> LDS
        const float4* wi4 = (const float4*)(W_ih0 + tid * HH);
        const float4* fw4 = (const float4*)ff_w;
        const float4* fb4 = (const float4*)ff_b;
        float vv = 0.f, uu = 0.f;
#pragma unroll
        for (int m = 0; m < HH / 4; ++m) {
            float4 a = wi4[m], fw = fw4[m], fb = fb4[m];
            vv += a.x * fw.x + a.y * fw.y + a.z * fw.z + a.w * fw.w;
            uu += a.x * fb.x + a.y * fb.y + a.z * fb.z + a.w * fb.w;
        }
        Vb[tid] = vv;
        Ub[tid] = uu + b0[tid];
        Bb[tid] = b1[tid];
    }

    const float* Wsrc = (grp == 0) ? W_hh0 : (grp == 1) ? W_ih1 : W_hh1;
    f16x8 Bw[2][4][4];  // [s][t2][kt] = 128 VGPRs (opaque-pinned below)
#pragma unroll
    for (int s = 0; s < 2; ++s)
#pragma unroll
        for (int t2 = 0; t2 < 4; ++t2) {
            const int r = t2 * HH + 32 * wg + 16 * s + c;
#pragma unroll
            for (int kt = 0; kt < 4; ++kt) Bw[s][t2][kt] = load_frag(Wsrc + r * HH, kt, lh);
        }
    // Opaque def: kills rematerialization -> fragments stay register-resident.
#pragma unroll
    for (int s = 0; s < 2; ++s)
#pragma unroll
        for (int t2 = 0; t2 < 4; ++t2)
#pragma unroll
            for (int kt = 0; kt < 4; ++kt)
                asm volatile("" : "+v"(Bw[s][t2][kt]));

    const int len = lengths[b];
    const bool ard = (c == 0);    // A-fragment reader lanes
    const bool mrow = (lh == 0);  // real output row (m=0) lanes
    float cst0[2] = {0.f, 0.f}, cst1[2] = {0.f, 0.f};
    float mean[2] = {0.f, 0.f}, mxv[2] = {-1e30f, -1e30f};
    f16x8 av[4];
#pragma unroll
    for (int kt = 0; kt < 4; ++kt) av[kt] = (f16x8){0, 0, 0, 0, 0, 0, 0, 0};
    __syncthreads();

    for (int i = 0; i <= len + 1; ++i) {
        const int rb = i & 1;
        if (grp == 0) {
            if (i < len) {
                if (ard) {
#pragma unroll
                    for (int kt = 0; kt < 4; ++kt)
                        av[kt] = *(const f16x8*)&Hb0[rb ^ 1][kt * 32 + lh * 8];
                }
                const float xt = xs[i];
#pragma unroll
                for (int s = 0; s < 2; ++s) {
                    const int ub = 32 * wg + 16 * s + c;
                    float p[4];
#pragma unroll
                    for (int t2 = 0; t2 < 4; ++t2) {
                        f32x4 a = (f32x4){0.f, 0.f, 0.f, 0.f};
#pragma unroll
                        for (int kt = 0; kt < 4; ++kt)
                            a = __builtin_amdgcn_mfma_f32_16x16x32_f16(
                                av[kt], Bw[s][t2][kt], a, 0, 0, 0);
                        p[t2] = a[0] + xt * Vb[t2 * HH + ub] + Ub[t2 * HH + ub];
                    }
                    float gi = sigm(p[0]), gf = sigm(p[1]);
                    float gg = tanh_f(p[2]), go = sigm(p[3]);
                    cst0[s] = gf * cst0[s] + gi * gg;
                    float h0n = go * tanh_f(cst0[s]);
                    if (mrow) Hb0[rb][ub] = (_Float16)h0n;
                }
            }
        } else if (grp == 1) {
            if (i >= 1 && i <= len) {
                if (ard) {
#pragma unroll
                    for (int kt = 0; kt < 4; ++kt)
                        av[kt] = *(const f16x8*)&Hb0[rb ^ 1][kt * 32 + lh * 8];
                }
#pragma unroll
                for (int s = 0; s < 2; ++s) {
                    const int ub = 32 * wg + 16 * s + c;
#pragma unroll
                    for (int t2 = 0; t2 < 4; ++t2) {
                        f32x4 a = (f32x4){0.f, 0.f, 0.f, 0.f};
#pragma unroll
                        for (int kt = 0; kt < 4; ++kt)
                            a = __builtin_amdgcn_mfma_f32_16x16x32_f16(
                                av[kt], Bw[s][t2][kt], a, 0, 0, 0);
                        if (mrow) Q1[rb][t2 * HH + ub] = a[0] + Bb[t2 * HH + ub];
                    }
                }
            }
        } else {
            if (i >= 2) {
                if (ard) {
#pragma unroll
                    for (int kt = 0; kt < 4; ++kt)
                        av[kt] = *(const f16x8*)&Hb1[rb ^ 1][kt * 32 + lh * 8];
                }
#pragma unroll
                for (int s = 0; s < 2; ++s) {
                    const int ub = 32 * wg + 16 * s + c;
                    float p[4];
#pragma unroll
                    for (int t2 = 0; t2 < 4; ++t2) {
                        f32x4 a = (f32x4){0.f, 0.f, 0.f, 0.f};
#pragma unroll
                        for (int kt = 0; kt < 4; ++kt)
                            a = __builtin_amdgcn_mfma_f32_16x16x32_f16(
                                av[kt], Bw[s][t2][kt], a, 0, 0, 0);
                        p[t2] = a[0] + Q1[rb ^ 1][t2 * HH + ub];
                    }
                    float gi = sigm(p[0]), gf = sigm(p[1]);
                    float gg = tanh_f(p[2]), go = sigm(p[3]);
                    cst1[s] = gf * cst1[s] + gi * gg;
                    float h1n = go * tanh_f(cst1[s]);
                    if (mrow) Hb1[rb][ub] = (_Float16)h1n;
                    mean[s] += h1n;
                    mxv[s] = fmaxf(mxv[s], h1n);
                }
            }
        }
        bar_lds();
    }

    if (grp == 2 && mrow) {
#pragma unroll
        for (int s = 0; s < 2; ++s) {
            const int ub = 32 * wg + 16 * s + c;
            // last = h1[len-1], written to Hb1[(len+1)&1] at interval len+1.
            pooled[b * 384 + ub] = mean[s] / (float)len;
            pooled[b * 384 + 128 + ub] = mxv[s];
            pooled[b * 384 + 256 + ub] = (float)Hb1[(len + 1) & 1][ub];
        }
    }
}

// ---------------- head: [B,3H] @ [3H,C]^T + bias ----------------
__global__ __launch_bounds__(448) void k_head(
    const float* __restrict__ pooled, const float* __restrict__ lin_w,
    const float* __restrict__ lin_b, float* __restrict__ out) {
    int tid = threadIdx.x;  // 448 = 64*7
    int b = tid / 7, cc = tid % 7;
    const float* p = pooled + b * 384;
    const float* wr = lin_w + cc * 384;
    float a0 = 0.f, a1 = 0.f, a2 = 0.f, a3 = 0.f;
#pragma unroll
    for (int k = 0; k < 384; k += 4) {
        a0 += p[k + 0] * wr[k + 0];
        a1 += p[k + 1] * wr[k + 1];
        a2 += p[k + 2] * wr[k + 2];
        a3 += p[k + 3] * wr[k + 3];
    }
    out[tid] = lin_b[cc] + ((a0 + a1) + (a2 + a3));
}

extern "C" void kernel_launch(void* const* d_in, const int* in_sizes, int n_in,
                              void* d_out, int out_size, void* d_ws, size_t ws_size,
                              hipStream_t stream) {
    const float* x     = (const float*)d_in[0];
    const int*   lens  = (const int*)d_in[1];
    const float* ff_w  = (const float*)d_in[2];
    const float* ff_b  = (const float*)d_in[3];
    const float* W_ih0 = (const float*)d_in[4];
    const float* W_hh0 = (const float*)d_in[5];
    const float* b0    = (const float*)d_in[6];
    const float* W_ih1 = (const float*)d_in[7];
    const float* W_hh1 = (const float*)d_in[8];
    const float* b1    = (const float*)d_in[9];
    const float* lin_w = (const float*)d_in[10];
    const float* lin_b = (const float*)d_in[11];
    float* out = (float*)d_out;

    float* pooled = (float*)d_ws;  // [64*384] floats

    k_mega<<<dim3(BB), dim3(768), 0, stream>>>(
        x, lens, ff_w, ff_b, W_ih0, W_hh0, b0, W_ih1, W_hh1, b1, pooled);
    k_head<<<dim3(1), dim3(448), 0, stream>>>(pooled, lin_w, lin_b, out);
}

// Round 11
// 2098.690 us; speedup vs baseline: 1.1265x; 1.1265x over previous
//
#include <hip/hip_runtime.h>
#include <hip/hip_fp16.h>

#define TT 2048
#define BB 64
#define HH 128
#define GG 512   // 4H
#define CH 64    // chunk (timesteps per handshake)
#define NCH (TT / CH)

typedef _Float16 f16x8 __attribute__((ext_vector_type(8)));
typedef _Float16 f16x4 __attribute__((ext_vector_type(4)));
typedef float f32x4 __attribute__((ext_vector_type(4)));

__device__ __forceinline__ float sigm(float x) {
    return __builtin_amdgcn_rcpf(1.0f + __expf(-x));
}
__device__ __forceinline__ float tanh_f(float x) {
    return 1.0f - 2.0f * __builtin_amdgcn_rcpf(1.0f + __expf(2.0f * x));
}
// LDS-only barrier: no vmcnt drain (HIP __syncthreads drains all global ops).
__device__ __forceinline__ void bar_lds() {
    asm volatile("s_waitcnt lgkmcnt(0)\n\ts_barrier" ::: "memory");
}

__device__ __forceinline__ f16x8 load_frag(const float* rowp, int kt, int lh) {
    const float4* p4 = (const float4*)(rowp + kt * 32 + lh * 8);
    float4 a = p4[0], b = p4[1];
    f16x8 f;
    f[0] = (_Float16)a.x; f[1] = (_Float16)a.y; f[2] = (_Float16)a.z; f[3] = (_Float16)a.w;
    f[4] = (_Float16)b.x; f[5] = (_Float16)b.y; f[6] = (_Float16)b.z; f[7] = (_Float16)b.w;
    return f;
}

// Producer/consumer pipeline across BLOCKS (not waves): grid = 128.
//   blocks 0..63   (batch b): layer-0 recurrence, r5's lean 8-wave shape
//     (64 frag VGPRs/wave -> never remats). Every CH steps: a small M=64 GEMM
//     q = b1 + W_ih1 . h0[chunk] (Bi reloaded per chunk, 64 MFMA/wave,
//     amortized ~5 cyc/step) -> Q in workspace -> release-flag (agent scope).
//   blocks 64..127 (batch b-64): layer-1 recurrence + pooling, acquire-polls
//     the chunk flag, then r5's 2-step-prefetch Q reads.
// Cross-XCD visibility via __hip_atomic release/acquire (G16). All 128 blocks
// co-resident (<=256 CUs) -> no deadlock. Flags are poison-safe (0xAAAAAAAA
// != ch+1) and re-set every launch (d_ws re-poisoned by harness).
__global__ __launch_bounds__(512, 1) void k_pipe(
    const float* __restrict__ x, const int* __restrict__ lengths,
    const float* __restrict__ ff_w, const float* __restrict__ ff_b,
    const float* __restrict__ W_ih0, const float* __restrict__ W_hh0,
    const float* __restrict__ b0, const float* __restrict__ W_ih1,
    const float* __restrict__ W_hh1, const float* __restrict__ b1,
    _Float16* __restrict__ Q, int* __restrict__ flags,
    float* __restrict__ pooled) {
    const int tid = threadIdx.x;
    const int w = tid >> 6;
    const int lane = tid & 63;
    const int c = lane & 15;
    const int lh = lane >> 4;
    const int un = 16 * w + c;
    const bool ard = (c == 0);     // A-frag reader lanes (M=1 row 0)
    const bool wr16 = (lane < 16); // C row m=0 lanes (lh==0)

    if (blockIdx.x < BB) {
        // ======================= PRODUCER: layer 0 =======================
        const int b = blockIdx.x;
        __shared__ float xs[TT];
        __shared__ _Float16 Hb0[2][HH];
        __shared__ _Float16 Hc[CH][136];  // chunk h0 history; +8 pad kills GEMM bank conflicts

        for (int i = tid; i < TT; i += 512) xs[i] = x[b * TT + i];
        if (tid < 2 * HH) ((_Float16*)Hb0)[tid] = (_Float16)0.f;

        f16x8 Bf[4][4];
        float v[4], u0[4], bb1[4];
#pragma unroll
        for (int t2 = 0; t2 < 4; ++t2) {
            const int r = t2 * HH + un;
#pragma unroll
            for (int kt = 0; kt < 4; ++kt) Bf[t2][kt] = load_frag(W_hh0 + r * HH, kt, lh);
            const float4* wi4 = (const float4*)(W_ih0 + r * HH);
            const float4* fw4 = (const float4*)ff_w;
            const float4* fb4 = (const float4*)ff_b;
            float vv = 0.f, uu = 0.f;
#pragma unroll
            for (int m = 0; m < HH / 4; ++m) {
                float4 a = wi4[m], fw = fw4[m], fb = fb4[m];
                vv += a.x * fw.x + a.y * fw.y + a.z * fw.z + a.w * fw.w;
                uu += a.x * fb.x + a.y * fb.y + a.z * fb.z + a.w * fb.w;
            }
            v[t2] = vv;
            u0[t2] = uu + b0[r];
            bb1[t2] = b1[r];
        }
        float cst0 = 0.f;
        f16x8 av[4];
#pragma unroll
        for (int kt = 0; kt < 4; ++kt) av[kt] = (f16x8){0, 0, 0, 0, 0, 0, 0, 0};
        __syncthreads();

        for (int ch = 0; ch < NCH; ++ch) {
            // ---- 64 serial recurrence steps ----
            for (int j = 0; j < CH; ++j) {
                const int t = ch * CH + j;
                const int rb = t & 1;
                if (ard) {
#pragma unroll
                    for (int kt = 0; kt < 4; ++kt)
                        av[kt] = *(const f16x8*)&Hb0[rb][kt * 32 + lh * 8];
                }
                const float xt = xs[t];
                float p[4];
#pragma unroll
                for (int t2 = 0; t2 < 4; ++t2) {
                    f32x4 a;
                    a[0] = wr16 ? (xt * v[t2] + u0[t2]) : 0.f;
                    a[1] = 0.f; a[2] = 0.f; a[3] = 0.f;
#pragma unroll
                    for (int kt = 0; kt < 4; ++kt)
                        a = __builtin_amdgcn_mfma_f32_16x16x32_f16(av[kt], Bf[t2][kt], a, 0, 0, 0);
                    p[t2] = a[0];
                }
                float gi = sigm(p[0]), gf = sigm(p[1]);
                float gg = tanh_f(p[2]), go = sigm(p[3]);
                cst0 = gf * cst0 + gi * gg;
                float h0n = go * tanh_f(cst0);
                if (wr16) {
                    Hb0[rb ^ 1][un] = (_Float16)h0n;
                    Hc[j][un] = (_Float16)h0n;
                }
                bar_lds();  // also publishes Hc[j] for the GEMM below
            }
            // ---- chunk GEMM: Q[t][un][t2] = b1 + W_ih1 . h0[t], t in chunk ----
            f16x8 Bi[4][4];  // reloaded per chunk: live range stays out of the step loop
#pragma unroll
            for (int t2 = 0; t2 < 4; ++t2)
#pragma unroll
                for (int kt = 0; kt < 4; ++kt)
                    Bi[t2][kt] = load_frag(W_ih1 + (t2 * HH + un) * HH, kt, lh);
#pragma unroll
            for (int mt = 0; mt < 4; ++mt) {
                f16x8 am[4];  // A[m=c][k=kt*32+lh*8+j] from padded Hc
#pragma unroll
                for (int kt = 0; kt < 4; ++kt)
                    am[kt] = *(const f16x8*)&Hc[mt * 16 + c][kt * 32 + lh * 8];
                f32x4 qa[4];
#pragma unroll
                for (int t2 = 0; t2 < 4; ++t2) {
                    qa[t2] = (f32x4){0.f, 0.f, 0.f, 0.f};
#pragma unroll
                    for (int kt = 0; kt < 4; ++kt)
                        qa[t2] = __builtin_amdgcn_mfma_f32_16x16x32_f16(am[kt], Bi[t2][kt], qa[t2], 0, 0, 0);
                }
#pragma unroll
                for (int r = 0; r < 4; ++r) {  // C row m = 4*lh + r, col un
                    f16x4 qv;
#pragma unroll
                    for (int t2 = 0; t2 < 4; ++t2) qv[t2] = (_Float16)(qa[t2][r] + bb1[t2]);
                    const size_t m = (size_t)b * TT + ch * CH + mt * 16 + 4 * lh + r;
                    __builtin_nontemporal_store(qv, (f16x4*)(Q + m * GG + un * 4));
                }
            }
            __syncthreads();  // drain every wave's Q stores before signaling
            if (tid == 0)
                __hip_atomic_store(&flags[b * NCH + ch], ch + 1, __ATOMIC_RELEASE,
                                   __HIP_MEMORY_SCOPE_AGENT);
        }
    } else {
        // ======================= CONSUMER: layer 1 =======================
        const int b = blockIdx.x - BB;
        __shared__ _Float16 Hb1[2][HH];
        if (tid < 2 * HH) ((_Float16*)Hb1)[tid] = (_Float16)0.f;

        f16x8 Bh[4][4];
#pragma unroll
        for (int t2 = 0; t2 < 4; ++t2)
#pragma unroll
            for (int kt = 0; kt < 4; ++kt)
                Bh[t2][kt] = load_frag(W_hh1 + (t2 * HH + un) * HH, kt, lh);

        const int len = lengths[b];
        float cst1 = 0.f, mean = 0.f, mx = -1e30f, last = 0.f;
        f16x8 av[4];
#pragma unroll
        for (int kt = 0; kt < 4; ++kt) av[kt] = (f16x8){0, 0, 0, 0, 0, 0, 0, 0};
        f16x4 gp0 = (f16x4){0, 0, 0, 0}, gp1 = (f16x4){0, 0, 0, 0};
        const size_t qbase = (size_t)b * TT * GG + un * 4;
        __syncthreads();

        for (int ch = 0; ch < NCH; ++ch) {
            if (tid == 0) {  // acquire gate: also invalidates this CU/XCD caches
                int guard = 0;
                while (__hip_atomic_load(&flags[b * NCH + ch], __ATOMIC_ACQUIRE,
                                         __HIP_MEMORY_SCOPE_AGENT) != ch + 1) {
                    __builtin_amdgcn_s_sleep(8);
                    if (++guard > (1 << 22)) break;  // hang guard (never trips if sync works)
                }
            }
            __syncthreads();
            const int t0 = ch * CH;
            if (wr16) {
                gp0 = *(const f16x4*)(Q + qbase + (size_t)(t0 + 0) * GG);
                gp1 = *(const f16x4*)(Q + qbase + (size_t)(t0 + 1) * GG);
            }
            for (int j = 0; j < CH; ++j) {
                const int t = t0 + j;
                const int rb = t & 1;
                const f16x4 gp = (j & 1) ? gp1 : gp0;
                if (ard) {
#pragma unroll
                    for (int kt = 0; kt < 4; ++kt)
                        av[kt] = *(const f16x8*)&Hb1[rb][kt * 32 + lh * 8];
                }
                if (wr16) {  // prefetch 2 ahead, clamped inside the flagged chunk
                    const int tp = (j + 2 < CH) ? t + 2 : t0 + CH - 1;
                    const f16x4 np = *(const f16x4*)(Q + qbase + (size_t)tp * GG);
                    if (j & 1) gp1 = np; else gp0 = np;
                }
                float p[4];
#pragma unroll
                for (int t2 = 0; t2 < 4; ++t2) {
                    f32x4 a;
                    a[0] = wr16 ? (float)gp[t2] : 0.f;
                    a[1] = 0.f; a[2] = 0.f; a[3] = 0.f;
#pragma unroll
                    for (int kt = 0; kt < 4; ++kt)
                        a = __builtin_amdgcn_mfma_f32_16x16x32_f16(av[kt], Bh[t2][kt], a, 0, 0, 0);
                    p[t2] = a[0];
                }
                float gi = sigm(p[0]), gf = sigm(p[1]);
                float gg = tanh_f(p[2]), go = sigm(p[3]);
                cst1 = gf * cst1 + gi * gg;
                float h1n = go * tanh_f(cst1);
                if (wr16) Hb1[rb ^ 1][un] = (_Float16)h1n;
                if (t < len) {
                    mean += h1n;
                    mx = fmaxf(mx, h1n);
                }
                if (t == len - 1) last = h1n;
                bar_lds();
            }
        }
        if (wr16) {
            pooled[b * 384 + un] = mean / (float)len;
            pooled[b * 384 + 128 + un] = mx;
            pooled[b * 384 + 256 + un] = last;
        }
    }
}

// ---------------- head: [B,3H] @ [3H,C]^T + bias ----------------
__global__ __launch_bounds__(448) void k_head(
    const float* __restrict__ pooled, const float* __restrict__ lin_w,
    const float* __restrict__ lin_b, float* __restrict__ out) {
    int tid = threadIdx.x;  // 448 = 64*7
    int b = tid / 7, cc = tid % 7;
    const float* p = pooled + b * 384;
    const float* wr = lin_w + cc * 384;
    float a0 = 0.f, a1 = 0.f, a2 = 0.f, a3 = 0.f;
#pragma unroll
    for (int k = 0; k < 384; k += 4) {
        a0 += p[k + 0] * wr[k + 0];
        a1 += p[k + 1] * wr[k + 1];
        a2 += p[k + 2] * wr[k + 2];
        a3 += p[k + 3] * wr[k + 3];
    }
    out[tid] = lin_b[cc] + ((a0 + a1) + (a2 + a3));
}

extern "C" void kernel_launch(void* const* d_in, const int* in_sizes, int n_in,
                              void* d_out, int out_size, void* d_ws, size_t ws_size,
                              hipStream_t stream) {
    const float* x     = (const float*)d_in[0];
    const int*   lens  = (const int*)d_in[1];
    const float* ff_w  = (const float*)d_in[2];
    const float* ff_b  = (const float*)d_in[3];
    const float* W_ih0 = (const float*)d_in[4];
    const float* W_hh0 = (const float*)d_in[5];
    const float* b0    = (const float*)d_in[6];
    const float* W_ih1 = (const float*)d_in[7];
    const float* W_hh1 = (const float*)d_in[8];
    const float* b1    = (const float*)d_in[9];
    const float* lin_w = (const float*)d_in[10];
    const float* lin_b = (const float*)d_in[11];
    float* out = (float*)d_out;

    char* ws = (char*)d_ws;
    const size_t QBYTES = (size_t)BB * TT * GG * 2;  // 128 MB fp16
    _Float16* Q  = (_Float16*)ws;
    int* flags   = (int*)(ws + QBYTES);               // 64*32 ints (poison-safe)
    float* pooled = (float*)(ws + QBYTES + 8192);     // [64*384]

    k_pipe<<<dim3(2 * BB), dim3(512), 0, stream>>>(
        x, lens, ff_w, ff_b, W_ih0, W_hh0, b0, W_ih1, W_hh1, b1, Q, flags, pooled);
    k_head<<<dim3(1), dim3(448), 0, stream>>>(pooled, lin_w, lin_b, out);
}

// Round 12
// 1384.006 us; speedup vs baseline: 1.7081x; 1.5164x over previous
//
#include <hip/hip_runtime.h>
#include <hip/hip_fp16.h>

#define TT 2048
#define BB 64
#define HH 128
#define GG 512   // 4H
#define CH 64    // chunk (timesteps per handshake)
#define NCH (TT / CH)

typedef _Float16 f16x8 __attribute__((ext_vector_type(8)));
typedef _Float16 f16x4 __attribute__((ext_vector_type(4)));
typedef float f32x4 __attribute__((ext_vector_type(4)));

__device__ __forceinline__ float sigm(float x) {
    return __builtin_amdgcn_rcpf(1.0f + __expf(-x));
}
__device__ __forceinline__ float tanh_f(float x) {
    return 1.0f - 2.0f * __builtin_amdgcn_rcpf(1.0f + __expf(2.0f * x));
}
// LDS-only barrier: no vmcnt drain (HIP __syncthreads drains all global ops).
__device__ __forceinline__ void bar_lds() {
    asm volatile("s_waitcnt lgkmcnt(0)\n\ts_barrier" ::: "memory");
}

__device__ __forceinline__ f16x8 load_frag(const float* rowp, int kt, int lh) {
    const float4* p4 = (const float4*)(rowp + kt * 32 + lh * 8);
    float4 a = p4[0], b = p4[1];
    f16x8 f;
    f[0] = (_Float16)a.x; f[1] = (_Float16)a.y; f[2] = (_Float16)a.z; f[3] = (_Float16)a.w;
    f[4] = (_Float16)b.x; f[5] = (_Float16)b.y; f[6] = (_Float16)b.z; f[7] = (_Float16)b.w;
    return f;
}

// Producer/consumer pipeline across blocks, grid = 128 (r11 protocol, proven
// correct). Round-12 rebalance:
//   producers 0..63: PURE r5-lstm0 recurrence (fastest measured: 1178
//     cyc/step, 64 resident frag VGPRs) + NT h0 store; per chunk: vmcnt-drain
//     (__syncthreads) + agent-release flag. No GEMM on the producer path.
//   consumers 64..127: per chunk: acquire flag -> M=64 GEMM (Bi reloaded per
//     chunk, A from global h0g) -> Qs in LDS -> 64 recurrence steps whose gate
//     inputs are LDS reads (no global traffic, no prefetch ping-pong — r11's
//     consumer stalled on conditional-register NT-HBM prefetch).
__global__ __launch_bounds__(512, 1) void k_pipe(
    const float* __restrict__ x, const int* __restrict__ lengths,
    const float* __restrict__ ff_w, const float* __restrict__ ff_b,
    const float* __restrict__ W_ih0, const float* __restrict__ W_hh0,
    const float* __restrict__ b0, const float* __restrict__ W_ih1,
    const float* __restrict__ W_hh1, const float* __restrict__ b1,
    _Float16* __restrict__ h0g, int* __restrict__ flags,
    float* __restrict__ pooled) {
    const int tid = threadIdx.x;
    const int w = tid >> 6;
    const int lane = tid & 63;
    const int c = lane & 15;
    const int lh = lane >> 4;
    const int un = 16 * w + c;
    const bool ard = (c == 0);     // A-frag reader lanes (M=1 row 0)
    const bool wr16 = (lane < 16); // C row m=0 lanes (lh==0)

    __shared__ float xs[TT];                 // producer
    __shared__ _Float16 Hb0[2][HH];          // producer
    __shared__ _Float16 Hb1[2][HH];          // consumer
    __shared__ _Float16 Qs[CH][GG];          // consumer: chunk gates (64 KB)

    if (blockIdx.x < BB) {
        // ======================= PRODUCER: layer 0 =======================
        const int b = blockIdx.x;
        for (int i = tid; i < TT; i += 512) xs[i] = x[b * TT + i];
        if (tid < 2 * HH) ((_Float16*)Hb0)[tid] = (_Float16)0.f;

        f16x8 Bf[4][4];
        float v[4], u0[4];
#pragma unroll
        for (int t2 = 0; t2 < 4; ++t2) {
            const int r = t2 * HH + un;
#pragma unroll
            for (int kt = 0; kt < 4; ++kt) Bf[t2][kt] = load_frag(W_hh0 + r * HH, kt, lh);
            const float4* wi4 = (const float4*)(W_ih0 + r * HH);
            const float4* fw4 = (const float4*)ff_w;
            const float4* fb4 = (const float4*)ff_b;
            float vv = 0.f, uu = 0.f;
#pragma unroll
            for (int m = 0; m < HH / 4; ++m) {
                float4 a = wi4[m], fw = fw4[m], fb = fb4[m];
                vv += a.x * fw.x + a.y * fw.y + a.z * fw.z + a.w * fw.w;
                uu += a.x * fb.x + a.y * fb.y + a.z * fb.z + a.w * fb.w;
            }
            v[t2] = vv;
            u0[t2] = uu + b0[r];
        }
#pragma unroll
        for (int t2 = 0; t2 < 4; ++t2)
#pragma unroll
            for (int kt = 0; kt < 4; ++kt) asm volatile("" : "+v"(Bf[t2][kt]));

        float cst0 = 0.f;
        f16x8 av[4];
#pragma unroll
        for (int kt = 0; kt < 4; ++kt) av[kt] = (f16x8){0, 0, 0, 0, 0, 0, 0, 0};
        __syncthreads();

#define PSTEP(T_, RB_)                                                          \
    do {                                                                        \
        if (ard) {                                                              \
            _Pragma("unroll") for (int kt = 0; kt < 4; ++kt)                    \
                av[kt] = *(const f16x8*)&Hb0[RB_][kt * 32 + lh * 8];            \
        }                                                                       \
        const float xt = xs[T_];                                                \
        float p[4];                                                             \
        _Pragma("unroll") for (int t2 = 0; t2 < 4; ++t2) {                      \
            f32x4 a;                                                            \
            a[0] = wr16 ? (xt * v[t2] + u0[t2]) : 0.f;                          \
            a[1] = 0.f; a[2] = 0.f; a[3] = 0.f;                                 \
            _Pragma("unroll") for (int kt = 0; kt < 4; ++kt)                    \
                a = __builtin_amdgcn_mfma_f32_16x16x32_f16(av[kt], Bf[t2][kt],  \
                                                           a, 0, 0, 0);         \
            p[t2] = a[0];                                                       \
        }                                                                       \
        float gi = sigm(p[0]), gf = sigm(p[1]);                                 \
        float gg = tanh_f(p[2]), go = sigm(p[3]);                               \
        cst0 = gf * cst0 + gi * gg;                                             \
        float h0n = go * tanh_f(cst0);                                          \
        if (wr16) {                                                             \
            Hb0[(RB_) ^ 1][un] = (_Float16)h0n;                                 \
            __builtin_nontemporal_store(                                        \
                (_Float16)h0n, h0g + ((size_t)b * TT + (T_)) * HH + un);        \
        }                                                                       \
        bar_lds();                                                              \
    } while (0)

        for (int ch = 0; ch < NCH; ++ch) {
            const int t0 = ch * CH;
            for (int j = 0; j < CH; j += 2) {
                PSTEP(t0 + j, 0);
                PSTEP(t0 + j + 1, 1);
            }
            __syncthreads();  // drain every wave's h0 NT stores before signaling
            if (tid == 0)
                __hip_atomic_store(&flags[b * NCH + ch], ch + 1, __ATOMIC_RELEASE,
                                   __HIP_MEMORY_SCOPE_AGENT);
        }
#undef PSTEP
    } else {
        // ======================= CONSUMER: layer 1 =======================
        const int b = blockIdx.x - BB;
        if (tid < 2 * HH) ((_Float16*)Hb1)[tid] = (_Float16)0.f;

        f16x8 Bh[4][4];
        float bb1[4];
#pragma unroll
        for (int t2 = 0; t2 < 4; ++t2) {
#pragma unroll
            for (int kt = 0; kt < 4; ++kt)
                Bh[t2][kt] = load_frag(W_hh1 + (t2 * HH + un) * HH, kt, lh);
            bb1[t2] = b1[t2 * HH + un];
        }
#pragma unroll
        for (int t2 = 0; t2 < 4; ++t2)
#pragma unroll
            for (int kt = 0; kt < 4; ++kt) asm volatile("" : "+v"(Bh[t2][kt]));

        const int len = lengths[b];
        float cst1 = 0.f, mean = 0.f, mx = -1e30f, last = 0.f;
        f16x8 av[4];
#pragma unroll
        for (int kt = 0; kt < 4; ++kt) av[kt] = (f16x8){0, 0, 0, 0, 0, 0, 0, 0};
        __syncthreads();

#define CSTEP(T_, RB_)                                                          \
    do {                                                                        \
        const int jj = (T_) & (CH - 1);                                         \
        f16x4 qv = *(const f16x4*)&Qs[jj][un * 4]; /* all lanes: broadcast */   \
        if (ard) {                                                              \
            _Pragma("unroll") for (int kt = 0; kt < 4; ++kt)                    \
                av[kt] = *(const f16x8*)&Hb1[RB_][kt * 32 + lh * 8];            \
        }                                                                       \
        float p[4];                                                             \
        _Pragma("unroll") for (int t2 = 0; t2 < 4; ++t2) {                      \
            f32x4 a;                                                            \
            a[0] = wr16 ? (float)qv[t2] : 0.f;                                  \
            a[1] = 0.f; a[2] = 0.f; a[3] = 0.f;                                 \
            _Pragma("unroll") for (int kt = 0; kt < 4; ++kt)                    \
                a = __builtin_amdgcn_mfma_f32_16x16x32_f16(av[kt], Bh[t2][kt],  \
                                                           a, 0, 0, 0);         \
            p[t2] = a[0];                                                       \
        }                                                                       \
        float gi = sigm(p[0]), gf = sigm(p[1]);                                 \
        float gg = tanh_f(p[2]), go = sigm(p[3]);                               \
        cst1 = gf * cst1 + gi * gg;                                             \
        float h1n = go * tanh_f(cst1);                                          \
        if (wr16) Hb1[(RB_) ^ 1][un] = (_Float16)h1n;                           \
        if ((T_) < len) {                                                       \
            mean += h1n;                                                        \
            mx = fmaxf(mx, h1n);                                                \
        }                                                                       \
        if ((T_) == len - 1) last = h1n;                                        \
        bar_lds();                                                              \
    } while (0)

        for (int ch = 0; ch < NCH; ++ch) {
            if (tid == 0) {  // acquire gate
                int guard = 0;
                while (__hip_atomic_load(&flags[b * NCH + ch], __ATOMIC_ACQUIRE,
                                         __HIP_MEMORY_SCOPE_AGENT) != ch + 1) {
                    __builtin_amdgcn_s_sleep(8);
                    if (++guard > (1 << 22)) break;  // hang guard
                }
            }
            __syncthreads();
            // ---- chunk GEMM: Qs[j][un*4+t2] = b1 + W_ih1 . h0[t0+j] ----
            f16x8 Bi[4][4];  // reloaded per chunk (keeps step-loop pressure low)
#pragma unroll
            for (int t2 = 0; t2 < 4; ++t2)
#pragma unroll
                for (int kt = 0; kt < 4; ++kt)
                    Bi[t2][kt] = load_frag(W_ih1 + (t2 * HH + un) * HH, kt, lh);
            const _Float16* hbase = h0g + ((size_t)b * TT + ch * CH) * HH;
#pragma unroll
            for (int mt = 0; mt < 4; ++mt) {
                f16x8 am[4];  // A[m=c][k=kt*32+lh*8+j]
#pragma unroll
                for (int kt = 0; kt < 4; ++kt)
                    am[kt] = *(const f16x8*)(hbase + (mt * 16 + c) * HH + kt * 32 + lh * 8);
                f32x4 qa[4];
#pragma unroll
                for (int t2 = 0; t2 < 4; ++t2) {
                    qa[t2] = (f32x4){0.f, 0.f, 0.f, 0.f};
#pragma unroll
                    for (int kt = 0; kt < 4; ++kt)
                        qa[t2] = __builtin_amdgcn_mfma_f32_16x16x32_f16(
                            am[kt], Bi[t2][kt], qa[t2], 0, 0, 0);
                }
#pragma unroll
                for (int r = 0; r < 4; ++r) {  // C row m = 4*lh + r
                    f16x4 qv;
#pragma unroll
                    for (int t2 = 0; t2 < 4; ++t2) qv[t2] = (_Float16)(qa[t2][r] + bb1[t2]);
                    *(f16x4*)&Qs[mt * 16 + 4 * lh + r][un * 4] = qv;
                }
            }
            __syncthreads();  // Qs visible to all waves
            // ---- 64 recurrence steps, gates from LDS ----
            const int t0 = ch * CH;
            for (int j = 0; j < CH; j += 2) {
                CSTEP(t0 + j, 0);
                CSTEP(t0 + j + 1, 1);
            }
        }
#undef CSTEP
        if (wr16) {
            pooled[b * 384 + un] = mean / (float)len;
            pooled[b * 384 + 128 + un] = mx;
            pooled[b * 384 + 256 + un] = last;
        }
    }
}

// ---------------- head: [B,3H] @ [3H,C]^T + bias ----------------
__global__ __launch_bounds__(448) void k_head(
    const float* __restrict__ pooled, const float* __restrict__ lin_w,
    const float* __restrict__ lin_b, float* __restrict__ out) {
    int tid = threadIdx.x;  // 448 = 64*7
    int b = tid / 7, cc = tid % 7;
    const float* p = pooled + b * 384;
    const float* wr = lin_w + cc * 384;
    float a0 = 0.f, a1 = 0.f, a2 = 0.f, a3 = 0.f;
#pragma unroll
    for (int k = 0; k < 384; k += 4) {
        a0 += p[k + 0] * wr[k + 0];
        a1 += p[k + 1] * wr[k + 1];
        a2 += p[k + 2] * wr[k + 2];
        a3 += p[k + 3] * wr[k + 3];
    }
    out[tid] = lin_b[cc] + ((a0 + a1) + (a2 + a3));
}

extern "C" void kernel_launch(void* const* d_in, const int* in_sizes, int n_in,
                              void* d_out, int out_size, void* d_ws, size_t ws_size,
                              hipStream_t stream) {
    const float* x     = (const float*)d_in[0];
    const int*   lens  = (const int*)d_in[1];
    const float* ff_w  = (const float*)d_in[2];
    const float* ff_b  = (const float*)d_in[3];
    const float* W_ih0 = (const float*)d_in[4];
    const float* W_hh0 = (const float*)d_in[5];
    const float* b0    = (const float*)d_in[6];
    const float* W_ih1 = (const float*)d_in[7];
    const float* W_hh1 = (const float*)d_in[8];
    const float* b1    = (const float*)d_in[9];
    const float* lin_w = (const float*)d_in[10];
    const float* lin_b = (const float*)d_in[11];
    float* out = (float*)d_out;

    char* ws = (char*)d_ws;
    const size_t HBYTES = (size_t)BB * TT * HH * 2;  // 32 MB fp16 h0
    _Float16* h0g = (_Float16*)ws;
    int* flags    = (int*)(ws + HBYTES);             // 64*32 ints (poison-safe)
    float* pooled = (float*)(ws + HBYTES + 8192);

    k_pipe<<<dim3(2 * BB), dim3(512), 0, stream>>>(
        x, lens, ff_w, ff_b, W_ih0, W_hh0, b0, W_ih1, W_hh1, b1, h0g, flags, pooled);
    k_head<<<dim3(1), dim3(448), 0, stream>>>(pooled, lin_w, lin_b, out);
}